// Round 7
// baseline (345.639 us; speedup 1.0000x reference)
//
#include <hip/hip_runtime.h>
#include <hip/hip_bf16.h>

#define N_ROWS 8192
#define DIM 512
#define C_CLSN 1000
#define C_PAD 1024
#define LOW_THRE (1.0f / 1000.0f)

typedef __bf16 bf16x8 __attribute__((ext_vector_type(8)));
typedef float floatx4 __attribute__((ext_vector_type(4)));
typedef unsigned long long ull;
typedef ull ull2 __attribute__((ext_vector_type(2)));

// v18 = v17 with the KE fragment read recast as ds_read_b128 (KG's measured
// conflict-free pattern) using the MFMA k-partition freedom:
//   MFMA m consumes k-bytes {16*lr + 8m .. +8} per lane row lr (A and B agree
//   on the partition -> exact same result, order-independent accumulation).
// Lane (lr,lc) reads 16B at g*1024 + lr*256 + lc*16: low 8B -> MFMA 0,
// high 8B -> MFMA 1. 48 ds_read_b128/block instead of 96 conflicting b64.

__device__ __forceinline__ void gl_lds16(const void* g, void* l) {
  __builtin_amdgcn_global_load_lds(
      (const __attribute__((address_space(1))) unsigned int*)g,
      (__attribute__((address_space(3))) unsigned int*)l, 16, 0, 0);
}

// Scrambled class->bit bijection (consistent across ALL producers/consumers):
//   word(c) = (c>>8)*4 + (c&3)   in [0,16)
//   bit(c)  = (c>>2) & 63

// ---------------- KZP: zero accum + detect conf storage + stable partition ---
__global__ __launch_bounds__(1024) void kzp_v18(const int* __restrict__ conf,
                                                int* __restrict__ perm,
                                                int* __restrict__ counters,
                                                int* __restrict__ zbase) {
  int tid = threadIdx.x;
  // zero S (8192) + scsim (8192) + counters (64) = 16448 ints (contiguous)
  for (int i = tid; i < 16448; i += 1024) zbase[i] = 0;
  __shared__ int sc[1024];
  __shared__ int sbad, sodd1, seven1, smode;
  if (tid == 0) { sbad = 0; sodd1 = 0; seven1 = 0; }
  __syncthreads();
  for (int i = tid; i < 2048; i += 1024) {
    int v = conf[i];
    if (v != 0 && v != 1) atomicOr(&sbad, 1);
    if (v == 1) { if (i & 1) atomicAdd(&sodd1, 1); else atomicAdd(&seven1, 1); }
  }
  __syncthreads();
  if (tid == 0) {
    int mode = 0;                                // int32 0/1
    if (sbad) mode = 1;                          // packed uint8 bools
    else if (seven1 > 0 && sodd1 == 0) mode = 2; // int64 0/1
    smode = mode;
  }
  __syncthreads();
  int mode = smode;
  int r0 = tid * 8;
  int f[8]; int cnt = 0;
  #pragma unroll
  for (int k = 0; k < 8; ++k) {
    int r = r0 + k;
    bool c;
    if (mode == 1)      c = ((const unsigned char*)conf)[r] != 0;
    else if (mode == 2) c = ((const long long*)conf)[r] != 0;
    else                c = conf[r] != 0;
    f[k] = c ? 1 : 0; cnt += f[k];
  }
  sc[tid] = cnt;
  __syncthreads();
  for (int off = 1; off < 1024; off <<= 1) {    // Hillis-Steele inclusive scan
    int v = (tid >= off) ? sc[tid - off] : 0;
    __syncthreads();
    sc[tid] += v;
    __syncthreads();
  }
  int incl = sc[tid];
  int excl = incl - cnt;
  int total = sc[1023];
  if (tid == 0) counters[3] = total;
  int cpos = excl;
  int npos = total + (r0 - excl);
  #pragma unroll
  for (int k = 0; k < 8; ++k) {
    if (f[k]) perm[cpos++] = r0 + k;
    else      perm[npos++] = r0 + k;
  }
}

// ---------------- KDA: prob scan + featnorm (v12 LINEAR stores) --------------
__global__ __launch_bounds__(256) void kda_v18(const float* __restrict__ prob,
                                               const float* __restrict__ feature,
                                               const int* __restrict__ perm,
                                               const int* __restrict__ counters_ro,
                                               ull* __restrict__ bits,
                                               int* __restrict__ top1a,
                                               int* __restrict__ cnta,
                                               __bf16* __restrict__ featBF,
                                               unsigned char* __restrict__ featF8) {
  int wv = threadIdx.x >> 6, lane = threadIdx.x & 63;
  int p = blockIdx.x * 4 + wv;
  int orig = perm[p];
  bool is_conf = p < counters_ro[3];           // partitioned: conf rows first
  const float4* pr4 = (const float4*)(prob + (size_t)orig * C_CLSN);
  float4 v[4];
  #pragma unroll
  for (int pass = 0; pass < 4; ++pass) {
    int q = pass * 64 + lane;
    v[pass] = (q < 250) ? pr4[q] : make_float4(-1.f, -1.f, -1.f, -1.f);
  }
  float bv = -1e30f; int bidx = 0x7fffffff;
  int cnt = 0;
  ull myword = 0ULL;
  #pragma unroll
  for (int pass = 0; pass < 4; ++pass) {
    int q = pass * 64 + lane;
    bool inb = q < 250;
    float el[4] = {v[pass].x, v[pass].y, v[pass].z, v[pass].w};
    #pragma unroll
    for (int j = 0; j < 4; ++j) {
      float pv = el[j];
      int c = q * 4 + j;
      if (inb && pv > bv) { bv = pv; bidx = c; }
      ull m = __ballot(inb && (pv > LOW_THRE));
      cnt += (int)__popcll(m);
      if (lane == pass * 4 + j) myword = m;
    }
  }
  #pragma unroll
  for (int m = 1; m < 64; m <<= 1) {
    float ov = __shfl_xor(bv, m); int oi = __shfl_xor(bidx, m);
    if (ov > bv || (ov == bv && oi < bidx)) { bv = ov; bidx = oi; }
  }
  int top1 = bidx;
  if (is_conf) {
    int w1 = ((top1 >> 8) << 2) | (top1 & 3);
    myword = (lane == w1) ? (1ULL << ((top1 >> 2) & 63)) : 0ULL;
  }
  if (lane < 16) bits[(size_t)p * 16 + lane] = myword;
  if (lane == 0) {
    top1a[p] = top1;
    cnta[p] = is_conf ? 0 : cnt;
  }
  // ---- feature normalize -> bf16 + fp8 (LINEAR coalesced stores) ----
  const float* fr = feature + (size_t)orig * DIM;
  int c0 = lane * 8;
  float4 v0 = *(const float4*)(fr + c0);
  float4 v1 = *(const float4*)(fr + c0 + 4);
  float ss = v0.x*v0.x + v0.y*v0.y + v0.z*v0.z + v0.w*v0.w
           + v1.x*v1.x + v1.y*v1.y + v1.z*v1.z + v1.w*v1.w;
  #pragma unroll
  for (int m = 1; m < 64; m <<= 1) ss += __shfl_xor(ss, m);
  float scl = 1.0f / fmaxf(sqrtf(ss), 1e-12f);
  float x0 = v0.x*scl, x1 = v0.y*scl, x2 = v0.z*scl, x3 = v0.w*scl;
  float x4 = v1.x*scl, x5 = v1.y*scl, x6 = v1.z*scl, x7 = v1.w*scl;
  bf16x8 bvx;
  bvx[0] = (__bf16)x0; bvx[1] = (__bf16)x1; bvx[2] = (__bf16)x2; bvx[3] = (__bf16)x3;
  bvx[4] = (__bf16)x4; bvx[5] = (__bf16)x5; bvx[6] = (__bf16)x6; bvx[7] = (__bf16)x7;
  *(bf16x8*)(featBF + (size_t)p * DIM + c0) = bvx;
  int lo = __builtin_amdgcn_cvt_pk_fp8_f32(x0, x1, 0, false);
  lo = __builtin_amdgcn_cvt_pk_fp8_f32(x2, x3, lo, true);
  int hi = __builtin_amdgcn_cvt_pk_fp8_f32(x4, x5, 0, false);
  hi = __builtin_amdgcn_cvt_pk_fp8_f32(x6, x7, hi, true);
  int2 pk; pk.x = lo; pk.y = hi;
  *(int2*)(featF8 + (size_t)p * DIM + c0) = pk;
}

// ---------------- KBC: proxy projection + normalize -> bf16 (v12 linear) -----
__global__ __launch_bounds__(256) void kbc_v18(const float* __restrict__ raw,
                                               const float* __restrict__ cP,
                                               __bf16* __restrict__ proxyBF) {
  int tid = threadIdx.x;
  int c0 = blockIdx.x * 8;
  int d0 = tid, d1 = tid + 256;
  if (c0 >= C_CLSN) {                          // zero-pad rows 1000..1023
    #pragma unroll
    for (int cc = 0; cc < 8; ++cc) {
      proxyBF[(size_t)(c0 + cc) * DIM + d0] = (__bf16)0.f;
      proxyBF[(size_t)(c0 + cc) * DIM + d1] = (__bf16)0.f;
    }
    return;
  }
  __shared__ float sraw[8 * DIM];  // 16 KB
  __shared__ float red[8 * 256];   // 8 KB
  for (int idx = tid; idx < 8 * DIM; idx += 256)
    sraw[idx] = raw[(size_t)c0 * DIM + idx];
  __syncthreads();
  float acc0[8], acc1[8];
  #pragma unroll
  for (int cc = 0; cc < 8; ++cc) { acc0[cc] = 0.f; acc1[cc] = 0.f; }
  for (int k = 0; k < DIM; k += 4) {
    float4 w0 = *(const float4*)&cP[(size_t)d0 * DIM + k];
    float4 w1 = *(const float4*)&cP[(size_t)d1 * DIM + k];
    #pragma unroll
    for (int cc = 0; cc < 8; ++cc) {
      const float* sr = &sraw[cc * DIM + k];
      acc0[cc] += sr[0]*w0.x + sr[1]*w0.y + sr[2]*w0.z + sr[3]*w0.w;
      acc1[cc] += sr[0]*w1.x + sr[1]*w1.y + sr[2]*w1.z + sr[3]*w1.w;
    }
  }
  #pragma unroll
  for (int cc = 0; cc < 8; ++cc)
    red[cc * 256 + tid] = acc0[cc]*acc0[cc] + acc1[cc]*acc1[cc];
  __syncthreads();
  for (int s = 128; s > 0; s >>= 1) {
    if (tid < s)
      #pragma unroll
      for (int cc = 0; cc < 8; ++cc)
        red[cc * 256 + tid] += red[cc * 256 + tid + s];
    __syncthreads();
  }
  #pragma unroll
  for (int cc = 0; cc < 8; ++cc) {
    float scl = 1.0f / fmaxf(sqrtf(red[cc * 256]), 1e-12f);
    proxyBF[(size_t)(c0 + cc) * DIM + d0] = (__bf16)(acc0[cc] * scl);
    proxyBF[(size_t)(c0 + cc) * DIM + d1] = (__bf16)(acc1[cc] * scl);
  }
}

// ---------------- KEGG: grid-partitioned fusion (v18) ------------------------
// v17 pipeline; KE fragment read is now ds_read_b128 at lr*256 + lc*16
// (KG's conflict-free pattern) with the m-partition trick.
__global__ __launch_bounds__(512, 4) void kegg_v18(const __bf16* __restrict__ featBF,
                                                   const __bf16* __restrict__ proxyBF,
                                                   const unsigned char* __restrict__ featF8,
                                                   const float* __restrict__ prob,
                                                   const ull* __restrict__ bits,
                                                   const int* __restrict__ perm,
                                                   const int* __restrict__ top1a,
                                                   const int* __restrict__ counters_ro,
                                                   float* __restrict__ scsim,
                                                   float* __restrict__ possim,
                                                   float* __restrict__ S) {
  __shared__ __align__(16) char smem[50176];
  int tid = threadIdx.x;
  int wv = tid >> 6, lane = tid & 63;
  int wi = wv >> 2, wj = wv & 3;            // 2x4 wave grid: 64 rows x 32 cols
  int lr = lane >> 4, lc = lane & 15;
  int sr_ = lane & 15, sc16 = lane >> 4;    // staging decomposition

  floatx4 acc[4][2];
  floatx4 zero = {0.f, 0.f, 0.f, 0.f};
  #pragma unroll
  for (int ti = 0; ti < 4; ++ti)
    #pragma unroll
    for (int tj = 0; tj < 2; ++tj) acc[ti][tj] = zero;

  if (blockIdx.x < 512) {
    // ================= KG path (bf16, BK=32, 16 iters) =================
    int* pO  = (int*)(smem + 32768);
    int* t1r = (int*)(smem + 33280);
    int bi = blockIdx.x >> 3;     // 64 row-tiles
    int bj = blockIdx.x & 7;      // 8 class-tiles
    const char* A = (const char*)featBF;    // linear 1024 B/row
    const char* B = (const char*)proxyBF;   // linear 1024 B/row
    size_t arow = (size_t)(bi * 128 + wv * 16 + sr_) * 1024 + sc16 * 16;
    size_t brow = (size_t)(bj * 128 + wv * 16 + sr_) * 1024 + sc16 * 16;
    // stage tile 0 FIRST (loads in flight during pO/t1r loads)
    gl_lds16(A + arow, smem + wv * 1024);
    gl_lds16(B + brow, smem + 8192 + wv * 1024);
    if (tid < 128) { pO[tid] = perm[bi * 128 + tid]; t1r[tid] = top1a[bi * 128 + tid]; }
    __syncthreads();
    for (int it = 0; it < 16; ++it) {
      int sel = it & 1;
      if (it < 15) {                       // prefetch tile it+1 into other buffer
        int ktb = (it + 1) * 64;           // bytes
        gl_lds16(A + arow + ktb, smem + (sel ^ 1) * 16384 + wv * 1024);
        gl_lds16(B + brow + ktb, smem + (sel ^ 1) * 16384 + 8192 + wv * 1024);
      }
      const char* bA = smem + sel * 16384;
      const char* bB = bA + 8192;
      bf16x8 afr[4], bfr[2];
      #pragma unroll
      for (int ti = 0; ti < 4; ++ti)
        afr[ti] = *(const bf16x8*)(bA + (wi * 4 + ti) * 1024 + lr * 256 + lc * 16);
      #pragma unroll
      for (int tj = 0; tj < 2; ++tj)
        bfr[tj] = *(const bf16x8*)(bB + (wj * 2 + tj) * 1024 + lr * 256 + lc * 16);
      #pragma unroll
      for (int ti = 0; ti < 4; ++ti)
        #pragma unroll
        for (int tj = 0; tj < 2; ++tj)
          acc[ti][tj] = __builtin_amdgcn_mfma_f32_16x16x32_bf16(afr[ti], bfr[tj], acc[ti][tj], 0, 0, 0);
      if (it < 15) __syncthreads();
    }
    #pragma unroll
    for (int ti = 0; ti < 4; ++ti) {
      int ibase = wi * 64 + ti * 16 + lr * 4;   // C/D: row=(lane>>4)*4+reg, col=lane&15
      float rs[4] = {0.f, 0.f, 0.f, 0.f};
      #pragma unroll
      for (int rr = 0; rr < 4; ++rr) {
        int il = ibase + rr;
        int orig = pO[il];
        int t1 = t1r[il];
        const float* prow = prob + (size_t)orig * C_CLSN;
        #pragma unroll
        for (int tj = 0; tj < 2; ++tj) {
          int c = bj * 128 + wj * 32 + tj * 16 + lc;
          float P = acc[ti][tj][rr];
          float pv = (c < C_CLSN) ? prow[c] : 0.f;
          if (pv > LOW_THRE) rs[rr] += pv * P;
          if (c == t1) possim[bi * 128 + il] = P;   // single writer grid-wide
        }
      }
      #pragma unroll
      for (int m = 1; m < 16; m <<= 1)
        #pragma unroll
        for (int rr = 0; rr < 4; ++rr) rs[rr] += __shfl_xor(rs[rr], m);
      if (lc == 0) {
        #pragma unroll
        for (int rr = 0; rr < 4; ++rr)
          atomicAdd(&scsim[bi * 128 + ibase + rr], rs[rr]);
      }
    }
    return;
  }

  // ================= KE path (fp8, BK=64, 8 iters) =================
  ull* bsI = (ull*)(smem + 32768);                    // dedicated 16 KB
  ull* bsJ = (ull*)smem;                              // POST-loop alias of A0/B0
  int* t1I = (int*)(smem + 49152);
  int* t1J = (int*)(smem + 49664);

  // LCG swizzle interleaves heavy (mode-3) and light tiles
  int b = (int)(((long long)(blockIdx.x - 512) * 997) % 2080);
  int bi = 0, rem = b;
  while (rem >= 64 - bi) { rem -= 64 - bi; bi++; }
  int bj = bi + rem;

  int nconf = counters_ro[3];
  bool allcI = (bi * 128 + 128) <= nconf;
  bool allcJ = (bj * 128 + 128) <= nconf;
  int mode = allcJ ? 0 : (allcI ? 1 : 3);   // bi<=bj + conf-first => allcJ -> allcI

  const char* F = (const char*)featF8;      // linear 512 B/row
  size_t arow = (size_t)(bi * 128 + wv * 16 + sr_) * 512 + sc16 * 16;
  size_t brow = (size_t)(bj * 128 + wv * 16 + sr_) * 512 + sc16 * 16;
  // stage tile 0 FIRST (in flight during t1/bsI loads)
  gl_lds16(F + arow, smem + wv * 1024);
  gl_lds16(F + brow, smem + 8192 + wv * 1024);
  if (tid < 128)      t1I[tid]       = top1a[bi * 128 + tid];
  else if (tid < 256) t1J[tid - 128] = top1a[bj * 128 + tid - 128];
  if (mode == 3) {    // bsI dedicated: stage before K-loop
    #pragma unroll
    for (int e = 0; e < 4; ++e) {
      int flat = tid + e * 512;
      int row = flat & 127, w = flat >> 7;
      bsI[w * 128 + row] = bits[(size_t)(bi * 128 + row) * 16 + w];
    }
  }
  __syncthreads();

  for (int it = 0; it < 8; ++it) {
    int sel = it & 1;
    if (it < 7) {                          // prefetch tile it+1 into other buffer
      int ktb = (it + 1) * 64;             // bytes
      gl_lds16(F + arow + ktb, smem + (sel ^ 1) * 16384 + wv * 1024);
      gl_lds16(F + brow + ktb, smem + (sel ^ 1) * 16384 + 8192 + wv * 1024);
    }
    const char* bA = smem + sel * 16384;
    const char* bB = bA + 8192;
    // b128 fragment read (conflict-free, KG pattern); m-partition:
    // MFMA m consumes per-lane k-bytes [16*lr + 8m, +8) -- A/B agree.
    ull2 av[4], bvv[2];
    #pragma unroll
    for (int ti = 0; ti < 4; ++ti)
      av[ti] = *(const ull2*)(bA + (wi * 4 + ti) * 1024 + lr * 256 + lc * 16);
    #pragma unroll
    for (int tj = 0; tj < 2; ++tj)
      bvv[tj] = *(const ull2*)(bB + (wj * 2 + tj) * 1024 + lr * 256 + lc * 16);
    #pragma unroll
    for (int m = 0; m < 2; ++m)
      #pragma unroll
      for (int ti = 0; ti < 4; ++ti)
        #pragma unroll
        for (int tj = 0; tj < 2; ++tj)
          acc[ti][tj] = __builtin_amdgcn_mfma_f32_16x16x32_fp8_fp8(
              (long)av[ti][m], (long)bvv[tj][m], acc[ti][tj], 0, 0, 0);
    if (it < 7) __syncthreads();
  }
  __syncthreads();              // all waves done reading A/B buffers
  if (mode != 0) {              // stage bsJ into the aliased region
    #pragma unroll
    for (int e = 0; e < 4; ++e) {
      int flat = tid + e * 512;
      int row = flat & 127, w = flat >> 7;
      bsJ[w * 128 + row] = bits[(size_t)(bj * 128 + row) * 16 + w];
    }
  }
  __syncthreads();

  int tJv[2];
  #pragma unroll
  for (int tj = 0; tj < 2; ++tj) tJv[tj] = t1J[wj * 32 + tj * 16 + lc];

  float cs[2] = {0.f, 0.f};     // mirror column partial sums
  #pragma unroll
  for (int ti = 0; ti < 4; ++ti) {
    int ibase = wi * 64 + ti * 16 + lr * 4;
    unsigned inter[8];
    if (mode == 0) {            // conf x conf: intersect <=> same top1
      #pragma unroll
      for (int rr = 0; rr < 4; ++rr) {
        int tI = t1I[ibase + rr];
        #pragma unroll
        for (int tj = 0; tj < 2; ++tj) inter[rr * 2 + tj] = (tI == tJv[tj]);
      }
    } else if (mode == 1) {     // conf-I: probe J's bitset (scrambled mapping)
      #pragma unroll
      for (int rr = 0; rr < 4; ++rr) {
        int tI = t1I[ibase + rr];
        int w = ((tI >> 8) << 2) | (tI & 3);
        int bb = (tI >> 2) & 63;
        #pragma unroll
        for (int tj = 0; tj < 2; ++tj) {
          ull word = bsJ[w * 128 + wj * 32 + tj * 16 + lc];
          inter[rr * 2 + tj] = (unsigned)((word >> bb) & 1ULL);
        }
      }
    } else {                    // general: full 1024-bit AND (mapping-agnostic)
      #pragma unroll
      for (int q = 0; q < 8; ++q) inter[q] = 0u;
      #pragma unroll
      for (int w = 0; w < 16; ++w) {
        ull2 a01 = *(const ull2*)&bsI[w * 128 + ibase];
        ull2 a23 = *(const ull2*)&bsI[w * 128 + ibase + 2];
        ull aw[4] = {a01[0], a01[1], a23[0], a23[1]};
        ull bw[2];
        #pragma unroll
        for (int tj = 0; tj < 2; ++tj) bw[tj] = bsJ[w * 128 + wj * 32 + tj * 16 + lc];
        #pragma unroll
        for (int rr = 0; rr < 4; ++rr)
          #pragma unroll
          for (int tj = 0; tj < 2; ++tj) {
            ull t = aw[rr] & bw[tj];
            inter[rr * 2 + tj] |= (unsigned)(t | (t >> 32));
          }
      }
    }
    float rs[4] = {0.f, 0.f, 0.f, 0.f};
    #pragma unroll
    for (int rr = 0; rr < 4; ++rr)
      #pragma unroll
      for (int tj = 0; tj < 2; ++tj) {
        float sim = acc[ti][tj][rr];
        sim = fminf(sim, 1.0f);   // unit rows: math no-op
        float e_ = ((inter[rr * 2 + tj] == 0u) && (sim >= 1e-6f)) ? __expf(sim) : 0.f;
        rs[rr] += e_;
        cs[tj] += e_;
      }
    #pragma unroll
    for (int m = 1; m < 16; m <<= 1)
      #pragma unroll
      for (int rr = 0; rr < 4; ++rr) rs[rr] += __shfl_xor(rs[rr], m);
    if (lc == 0) {
      #pragma unroll
      for (int rr = 0; rr < 4; ++rr)
        atomicAdd(&S[(size_t)bi * 128 + ibase + rr], rs[rr]);
    }
  }
  if (bi != bj) {   // mirror: (j,i) identical by symmetry -> column sums
    #pragma unroll
    for (int tj = 0; tj < 2; ++tj) {
      cs[tj] += __shfl_xor(cs[tj], 16);   // reduce over lr
      cs[tj] += __shfl_xor(cs[tj], 32);
    }
    if (lr == 0) {
      #pragma unroll
      for (int tj = 0; tj < 2; ++tj)
        atomicAdd(&S[(size_t)bj * 128 + wj * 32 + tj * 16 + lc], cs[tj]);
    }
  }
}

// ---------------- KF: final reduction (loss + sc_num) — fp32 out -------------
__global__ __launch_bounds__(1024) void kf_final_v18(const float* __restrict__ possim,
                                                     const float* __restrict__ scsim,
                                                     const float* __restrict__ S,
                                                     const int* __restrict__ cnta,
                                                     const int* __restrict__ counters,
                                                     float* __restrict__ out) {
  __shared__ float red[1024];
  __shared__ int redi[1024];
  int tid = threadIdx.x;
  int nconf = counters[3];
  float local = 0.f;
  int lcnt = 0;
  for (int i = tid; i < N_ROWS; i += 1024) {
    float p = (i < nconf) ? possim[i] : scsim[i];
    p = fminf(fmaxf(p, -1.1f), 1.1f);      // |pos|<=1 math bound (safety)
    float s = fmaxf(S[i], 0.0f);
    local += logf(expf(p) + s) - p;        // -logp[:,0]
    lcnt += cnta[i];
  }
  red[tid] = local;
  redi[tid] = lcnt;
  __syncthreads();
  for (int s = 512; s > 0; s >>= 1) {
    if (tid < s) { red[tid] += red[tid + s]; redi[tid] += redi[tid + s]; }
    __syncthreads();
  }
  if (tid == 0) {
    float loss = red[0] / (float)N_ROWS;
    int denom = N_ROWS - nconf;            // exact: count of non-conf rows
    int scc = redi[0];
    float scn = (denom > 0) ? ((float)scc / (float)denom) : 0.f;
    out[0] = loss;
    out[1] = scn;
  }
}

extern "C" void kernel_launch(void* const* d_in, const int* in_sizes, int n_in,
                              void* d_out, int out_size, void* d_ws, size_t ws_size,
                              hipStream_t stream) {
  const float* feature   = (const float*)d_in[0];
  const float* proxy_raw = (const float*)d_in[1];
  const float* cP        = (const float*)d_in[2];
  const float* prob      = (const float*)d_in[3];
  const int*   conf      = (const int*)d_in[4];
  float* out = (float*)d_out;

  size_t need = (size_t)N_ROWS * DIM * 2      // featBF    8 MB (linear)
              + (size_t)N_ROWS * DIM          // featF8    4 MB (linear)
              + (size_t)C_PAD * DIM * 2       // proxyBF   1 MB (linear)
              + (size_t)N_ROWS * 16 * 8       // bits      1 MB
              + (size_t)N_ROWS * 4            // possim
              + (size_t)N_ROWS * 4            // S
              + (size_t)N_ROWS * 4            // scsim
              + 256                           // counters
              + (size_t)N_ROWS * 4            // perm
              + (size_t)N_ROWS * 4            // top1a
              + (size_t)N_ROWS * 4;           // cnta
  if (ws_size < need) return;

  char* ws = (char*)d_ws;
  __bf16* featBF  = (__bf16*)ws;              ws += (size_t)N_ROWS * DIM * 2;
  unsigned char* featF8 = (unsigned char*)ws; ws += (size_t)N_ROWS * DIM;
  __bf16* proxyBF = (__bf16*)ws;              ws += (size_t)C_PAD * DIM * 2;
  ull* bits       = (ull*)ws;                 ws += (size_t)N_ROWS * 16 * 8;
  float* possim   = (float*)ws;               ws += (size_t)N_ROWS * 4;
  float* S        = (float*)ws;               ws += (size_t)N_ROWS * 4;  // S,scsim,counters contiguous
  float* scsim    = (float*)ws;               ws += (size_t)N_ROWS * 4;
  int* counters   = (int*)ws;                 ws += 256;  // [3]=nconf
  int* perm       = (int*)ws;                 ws += (size_t)N_ROWS * 4;
  int* top1a      = (int*)ws;                 ws += (size_t)N_ROWS * 4;
  int* cnta       = (int*)ws;                 ws += (size_t)N_ROWS * 4;

  // kzp zeroes S+scsim+counters in-kernel (memset dispatch removed)
  kzp_v18<<<1, 1024, 0, stream>>>(conf, perm, counters, (int*)S);
  kda_v18<<<N_ROWS / 4, 256, 0, stream>>>(prob, feature, perm, counters,
                                          bits, top1a, cnta, featBF, featF8);
  kbc_v18<<<C_PAD / 8, 256, 0, stream>>>(proxy_raw, cP, proxyBF);
  kegg_v18<<<512 + 2080, 512, 0, stream>>>(featBF, proxyBF, featF8, prob, bits, perm,
                                           top1a, counters, scsim, possim, S);
  kf_final_v18<<<1, 1024, 0, stream>>>(possim, scsim, S, cnta, counters, out);
}

// Round 8
// 341.831 us; speedup vs baseline: 1.0111x; 1.0111x over previous
//
#include <hip/hip_runtime.h>
#include <hip/hip_bf16.h>

#define N_ROWS 8192
#define DIM 512
#define C_CLSN 1000
#define C_PAD 1024
#define LOW_THRE (1.0f / 1000.0f)

typedef __bf16 bf16x8 __attribute__((ext_vector_type(8)));
typedef float floatx4 __attribute__((ext_vector_type(4)));
typedef unsigned long long ull;
typedef ull ull2 __attribute__((ext_vector_type(2)));

// v19 = v18 with T4 counted-vmcnt K-loops (m218): 3-buffer LDS rotation,
// ONE raw s_barrier per K-step, s_waitcnt vmcnt(2) (never 0 until the last
// iter) so prefetch loads stay in flight ACROSS barriers. Per iter t:
//   vmcnt(2)  -> tile t (oldest) landed, tile t+1 still flying
//   s_barrier -> all waves certified tile t in LDS
//   issue t+2 -> into buf[(t+2)%3] (all waves consumed it at t-1, pre-barrier)
//   consume buf[t%3]
// LDS: 3 x 16KB staging + t1 = ~50KB -> 3 blocks/CU (unchanged).
// bsI joins bsJ post-loop in the dead staging space.

__device__ __forceinline__ void gl_lds16(const void* g, void* l) {
  __builtin_amdgcn_global_load_lds(
      (const __attribute__((address_space(1))) unsigned int*)g,
      (__attribute__((address_space(3))) unsigned int*)l, 16, 0, 0);
}

// Scrambled class->bit bijection (consistent across ALL producers/consumers):
//   word(c) = (c>>8)*4 + (c&3)   in [0,16)
//   bit(c)  = (c>>2) & 63

// ---------------- KZP: zero accum + detect conf storage + stable partition ---
__global__ __launch_bounds__(1024) void kzp_v19(const int* __restrict__ conf,
                                                int* __restrict__ perm,
                                                int* __restrict__ counters,
                                                int* __restrict__ zbase) {
  int tid = threadIdx.x;
  for (int i = tid; i < 16448; i += 1024) zbase[i] = 0;
  __shared__ int sc[1024];
  __shared__ int sbad, sodd1, seven1, smode;
  if (tid == 0) { sbad = 0; sodd1 = 0; seven1 = 0; }
  __syncthreads();
  for (int i = tid; i < 2048; i += 1024) {
    int v = conf[i];
    if (v != 0 && v != 1) atomicOr(&sbad, 1);
    if (v == 1) { if (i & 1) atomicAdd(&sodd1, 1); else atomicAdd(&seven1, 1); }
  }
  __syncthreads();
  if (tid == 0) {
    int mode = 0;
    if (sbad) mode = 1;
    else if (seven1 > 0 && sodd1 == 0) mode = 2;
    smode = mode;
  }
  __syncthreads();
  int mode = smode;
  int r0 = tid * 8;
  int f[8]; int cnt = 0;
  #pragma unroll
  for (int k = 0; k < 8; ++k) {
    int r = r0 + k;
    bool c;
    if (mode == 1)      c = ((const unsigned char*)conf)[r] != 0;
    else if (mode == 2) c = ((const long long*)conf)[r] != 0;
    else                c = conf[r] != 0;
    f[k] = c ? 1 : 0; cnt += f[k];
  }
  sc[tid] = cnt;
  __syncthreads();
  for (int off = 1; off < 1024; off <<= 1) {
    int v = (tid >= off) ? sc[tid - off] : 0;
    __syncthreads();
    sc[tid] += v;
    __syncthreads();
  }
  int incl = sc[tid];
  int excl = incl - cnt;
  int total = sc[1023];
  if (tid == 0) counters[3] = total;
  int cpos = excl;
  int npos = total + (r0 - excl);
  #pragma unroll
  for (int k = 0; k < 8; ++k) {
    if (f[k]) perm[cpos++] = r0 + k;
    else      perm[npos++] = r0 + k;
  }
}

// ---------------- KDA: prob scan + featnorm (linear stores) ------------------
__global__ __launch_bounds__(256) void kda_v19(const float* __restrict__ prob,
                                               const float* __restrict__ feature,
                                               const int* __restrict__ perm,
                                               const int* __restrict__ counters_ro,
                                               ull* __restrict__ bits,
                                               int* __restrict__ top1a,
                                               int* __restrict__ cnta,
                                               __bf16* __restrict__ featBF,
                                               unsigned char* __restrict__ featF8) {
  int wv = threadIdx.x >> 6, lane = threadIdx.x & 63;
  int p = blockIdx.x * 4 + wv;
  int orig = perm[p];
  bool is_conf = p < counters_ro[3];
  const float4* pr4 = (const float4*)(prob + (size_t)orig * C_CLSN);
  float4 v[4];
  #pragma unroll
  for (int pass = 0; pass < 4; ++pass) {
    int q = pass * 64 + lane;
    v[pass] = (q < 250) ? pr4[q] : make_float4(-1.f, -1.f, -1.f, -1.f);
  }
  float bv = -1e30f; int bidx = 0x7fffffff;
  int cnt = 0;
  ull myword = 0ULL;
  #pragma unroll
  for (int pass = 0; pass < 4; ++pass) {
    int q = pass * 64 + lane;
    bool inb = q < 250;
    float el[4] = {v[pass].x, v[pass].y, v[pass].z, v[pass].w};
    #pragma unroll
    for (int j = 0; j < 4; ++j) {
      float pv = el[j];
      int c = q * 4 + j;
      if (inb && pv > bv) { bv = pv; bidx = c; }
      ull m = __ballot(inb && (pv > LOW_THRE));
      cnt += (int)__popcll(m);
      if (lane == pass * 4 + j) myword = m;
    }
  }
  #pragma unroll
  for (int m = 1; m < 64; m <<= 1) {
    float ov = __shfl_xor(bv, m); int oi = __shfl_xor(bidx, m);
    if (ov > bv || (ov == bv && oi < bidx)) { bv = ov; bidx = oi; }
  }
  int top1 = bidx;
  if (is_conf) {
    int w1 = ((top1 >> 8) << 2) | (top1 & 3);
    myword = (lane == w1) ? (1ULL << ((top1 >> 2) & 63)) : 0ULL;
  }
  if (lane < 16) bits[(size_t)p * 16 + lane] = myword;
  if (lane == 0) {
    top1a[p] = top1;
    cnta[p] = is_conf ? 0 : cnt;
  }
  const float* fr = feature + (size_t)orig * DIM;
  int c0 = lane * 8;
  float4 v0 = *(const float4*)(fr + c0);
  float4 v1 = *(const float4*)(fr + c0 + 4);
  float ss = v0.x*v0.x + v0.y*v0.y + v0.z*v0.z + v0.w*v0.w
           + v1.x*v1.x + v1.y*v1.y + v1.z*v1.z + v1.w*v1.w;
  #pragma unroll
  for (int m = 1; m < 64; m <<= 1) ss += __shfl_xor(ss, m);
  float scl = 1.0f / fmaxf(sqrtf(ss), 1e-12f);
  float x0 = v0.x*scl, x1 = v0.y*scl, x2 = v0.z*scl, x3 = v0.w*scl;
  float x4 = v1.x*scl, x5 = v1.y*scl, x6 = v1.z*scl, x7 = v1.w*scl;
  bf16x8 bvx;
  bvx[0] = (__bf16)x0; bvx[1] = (__bf16)x1; bvx[2] = (__bf16)x2; bvx[3] = (__bf16)x3;
  bvx[4] = (__bf16)x4; bvx[5] = (__bf16)x5; bvx[6] = (__bf16)x6; bvx[7] = (__bf16)x7;
  *(bf16x8*)(featBF + (size_t)p * DIM + c0) = bvx;
  int lo = __builtin_amdgcn_cvt_pk_fp8_f32(x0, x1, 0, false);
  lo = __builtin_amdgcn_cvt_pk_fp8_f32(x2, x3, lo, true);
  int hi = __builtin_amdgcn_cvt_pk_fp8_f32(x4, x5, 0, false);
  hi = __builtin_amdgcn_cvt_pk_fp8_f32(x6, x7, hi, true);
  int2 pk; pk.x = lo; pk.y = hi;
  *(int2*)(featF8 + (size_t)p * DIM + c0) = pk;
}

// ---------------- KBC: proxy projection + normalize -> bf16 (linear) ---------
__global__ __launch_bounds__(256) void kbc_v19(const float* __restrict__ raw,
                                               const float* __restrict__ cP,
                                               __bf16* __restrict__ proxyBF) {
  int tid = threadIdx.x;
  int c0 = blockIdx.x * 8;
  int d0 = tid, d1 = tid + 256;
  if (c0 >= C_CLSN) {
    #pragma unroll
    for (int cc = 0; cc < 8; ++cc) {
      proxyBF[(size_t)(c0 + cc) * DIM + d0] = (__bf16)0.f;
      proxyBF[(size_t)(c0 + cc) * DIM + d1] = (__bf16)0.f;
    }
    return;
  }
  __shared__ float sraw[8 * DIM];  // 16 KB
  __shared__ float red[8 * 256];   // 8 KB
  for (int idx = tid; idx < 8 * DIM; idx += 256)
    sraw[idx] = raw[(size_t)c0 * DIM + idx];
  __syncthreads();
  float acc0[8], acc1[8];
  #pragma unroll
  for (int cc = 0; cc < 8; ++cc) { acc0[cc] = 0.f; acc1[cc] = 0.f; }
  for (int k = 0; k < DIM; k += 4) {
    float4 w0 = *(const float4*)&cP[(size_t)d0 * DIM + k];
    float4 w1 = *(const float4*)&cP[(size_t)d1 * DIM + k];
    #pragma unroll
    for (int cc = 0; cc < 8; ++cc) {
      const float* sr = &sraw[cc * DIM + k];
      acc0[cc] += sr[0]*w0.x + sr[1]*w0.y + sr[2]*w0.z + sr[3]*w0.w;
      acc1[cc] += sr[0]*w1.x + sr[1]*w1.y + sr[2]*w1.z + sr[3]*w1.w;
    }
  }
  #pragma unroll
  for (int cc = 0; cc < 8; ++cc)
    red[cc * 256 + tid] = acc0[cc]*acc0[cc] + acc1[cc]*acc1[cc];
  __syncthreads();
  for (int s = 128; s > 0; s >>= 1) {
    if (tid < s)
      #pragma unroll
      for (int cc = 0; cc < 8; ++cc)
        red[cc * 256 + tid] += red[cc * 256 + tid + s];
    __syncthreads();
  }
  #pragma unroll
  for (int cc = 0; cc < 8; ++cc) {
    float scl = 1.0f / fmaxf(sqrtf(red[cc * 256]), 1e-12f);
    proxyBF[(size_t)(c0 + cc) * DIM + d0] = (__bf16)(acc0[cc] * scl);
    proxyBF[(size_t)(c0 + cc) * DIM + d1] = (__bf16)(acc1[cc] * scl);
  }
}

// ---------------- KEGG: grid-partitioned fusion (v19: counted-vmcnt) ---------
__global__ __launch_bounds__(512, 4) void kegg_v19(const __bf16* __restrict__ featBF,
                                                   const __bf16* __restrict__ proxyBF,
                                                   const unsigned char* __restrict__ featF8,
                                                   const float* __restrict__ prob,
                                                   const ull* __restrict__ bits,
                                                   const int* __restrict__ perm,
                                                   const int* __restrict__ top1a,
                                                   const int* __restrict__ counters_ro,
                                                   float* __restrict__ scsim,
                                                   float* __restrict__ possim,
                                                   float* __restrict__ S) {
  __shared__ __align__(16) char smem[50176];
  int tid = threadIdx.x;
  int wv = tid >> 6, lane = tid & 63;
  int wi = wv >> 2, wj = wv & 3;            // 2x4 wave grid: 64 rows x 32 cols
  int lr = lane >> 4, lc = lane & 15;
  int sr_ = lane & 15, sc16 = lane >> 4;    // staging decomposition

  floatx4 acc[4][2];
  floatx4 zero = {0.f, 0.f, 0.f, 0.f};
  #pragma unroll
  for (int ti = 0; ti < 4; ++ti)
    #pragma unroll
    for (int tj = 0; tj < 2; ++tj) acc[ti][tj] = zero;

  if (blockIdx.x < 512) {
    // ================= KG path (bf16, BK=32, 16 iters, 3-buf) =================
    int* pO  = (int*)(smem + 49152);
    int* t1r = (int*)(smem + 49664);
    int bi = blockIdx.x >> 3;
    int bj = blockIdx.x & 7;
    const char* A = (const char*)featBF;    // linear 1024 B/row
    const char* B = (const char*)proxyBF;   // linear 1024 B/row
    size_t arow = (size_t)(bi * 128 + wv * 16 + sr_) * 1024 + sc16 * 16;
    size_t brow = (size_t)(bj * 128 + wv * 16 + sr_) * 1024 + sc16 * 16;
    // prefetch tiles 0,1 (no prologue barrier: K-loop barriers certify)
    gl_lds16(A + arow,      smem + wv * 1024);
    gl_lds16(B + brow,      smem + 8192 + wv * 1024);
    gl_lds16(A + arow + 64, smem + 16384 + wv * 1024);
    gl_lds16(B + brow + 64, smem + 16384 + 8192 + wv * 1024);
    if (tid < 128) { pO[tid] = perm[bi * 128 + tid]; t1r[tid] = top1a[bi * 128 + tid]; }
    #pragma unroll
    for (int it = 0; it < 16; ++it) {
      if (it < 15) asm volatile("s_waitcnt vmcnt(2)" ::: "memory");
      else         asm volatile("s_waitcnt vmcnt(0)" ::: "memory");
      __builtin_amdgcn_s_barrier();
      if (it < 14) {                       // issue tile it+2 into buf[(it+2)%3]
        int ktb = (it + 2) * 64;
        char* dst = smem + ((it + 2) % 3) * 16384;
        gl_lds16(A + arow + ktb, dst + wv * 1024);
        gl_lds16(B + brow + ktb, dst + 8192 + wv * 1024);
      }
      const char* bA = smem + (it % 3) * 16384;
      const char* bB = bA + 8192;
      bf16x8 afr[4], bfr[2];
      #pragma unroll
      for (int ti = 0; ti < 4; ++ti)
        afr[ti] = *(const bf16x8*)(bA + (wi * 4 + ti) * 1024 + lr * 256 + lc * 16);
      #pragma unroll
      for (int tj = 0; tj < 2; ++tj)
        bfr[tj] = *(const bf16x8*)(bB + (wj * 2 + tj) * 1024 + lr * 256 + lc * 16);
      #pragma unroll
      for (int ti = 0; ti < 4; ++ti)
        #pragma unroll
        for (int tj = 0; tj < 2; ++tj)
          acc[ti][tj] = __builtin_amdgcn_mfma_f32_16x16x32_bf16(afr[ti], bfr[tj], acc[ti][tj], 0, 0, 0);
    }
    #pragma unroll
    for (int ti = 0; ti < 4; ++ti) {
      int ibase = wi * 64 + ti * 16 + lr * 4;   // C/D: row=(lane>>4)*4+reg, col=lane&15
      float rs[4] = {0.f, 0.f, 0.f, 0.f};
      #pragma unroll
      for (int rr = 0; rr < 4; ++rr) {
        int il = ibase + rr;
        int orig = pO[il];
        int t1 = t1r[il];
        const float* prow = prob + (size_t)orig * C_CLSN;
        #pragma unroll
        for (int tj = 0; tj < 2; ++tj) {
          int c = bj * 128 + wj * 32 + tj * 16 + lc;
          float P = acc[ti][tj][rr];
          float pv = (c < C_CLSN) ? prow[c] : 0.f;
          if (pv > LOW_THRE) rs[rr] += pv * P;
          if (c == t1) possim[bi * 128 + il] = P;   // single writer grid-wide
        }
      }
      #pragma unroll
      for (int m = 1; m < 16; m <<= 1)
        #pragma unroll
        for (int rr = 0; rr < 4; ++rr) rs[rr] += __shfl_xor(rs[rr], m);
      if (lc == 0) {
        #pragma unroll
        for (int rr = 0; rr < 4; ++rr)
          atomicAdd(&scsim[bi * 128 + ibase + rr], rs[rr]);
      }
    }
    return;
  }

  // ================= KE path (fp8, BK=64, 8 iters, 3-buf) =================
  ull* bsI = (ull*)smem;                              // POST-loop alias buf0
  ull* bsJ = (ull*)(smem + 16384);                    // POST-loop alias buf1
  int* t1I = (int*)(smem + 49152);
  int* t1J = (int*)(smem + 49664);

  // LCG swizzle interleaves heavy (mode-3) and light tiles
  int b = (int)(((long long)(blockIdx.x - 512) * 997) % 2080);
  int bi = 0, rem = b;
  while (rem >= 64 - bi) { rem -= 64 - bi; bi++; }
  int bj = bi + rem;

  int nconf = counters_ro[3];
  bool allcI = (bi * 128 + 128) <= nconf;
  bool allcJ = (bj * 128 + 128) <= nconf;
  int mode = allcJ ? 0 : (allcI ? 1 : 3);

  const char* F = (const char*)featF8;      // linear 512 B/row
  size_t arow = (size_t)(bi * 128 + wv * 16 + sr_) * 512 + sc16 * 16;
  size_t brow = (size_t)(bj * 128 + wv * 16 + sr_) * 512 + sc16 * 16;
  // prefetch tiles 0,1
  gl_lds16(F + arow,      smem + wv * 1024);
  gl_lds16(F + brow,      smem + 8192 + wv * 1024);
  gl_lds16(F + arow + 64, smem + 16384 + wv * 1024);
  gl_lds16(F + brow + 64, smem + 16384 + 8192 + wv * 1024);
  if (tid < 128)      t1I[tid]       = top1a[bi * 128 + tid];
  else if (tid < 256) t1J[tid - 128] = top1a[bj * 128 + tid - 128];

  #pragma unroll
  for (int it = 0; it < 8; ++it) {
    if (it < 7) asm volatile("s_waitcnt vmcnt(2)" ::: "memory");
    else        asm volatile("s_waitcnt vmcnt(0)" ::: "memory");
    __builtin_amdgcn_s_barrier();
    if (it < 6) {                          // issue tile it+2 into buf[(it+2)%3]
      int ktb = (it + 2) * 64;
      char* dst = smem + ((it + 2) % 3) * 16384;
      gl_lds16(F + arow + ktb, dst + wv * 1024);
      gl_lds16(F + brow + ktb, dst + 8192 + wv * 1024);
    }
    const char* bA = smem + (it % 3) * 16384;
    const char* bB = bA + 8192;
    // b128 fragment read (conflict-free); m-partition: MFMA m consumes
    // per-lane k-bytes [16*lr + 8m, +8) -- A/B agree -> exact result.
    ull2 av[4], bvv[2];
    #pragma unroll
    for (int ti = 0; ti < 4; ++ti)
      av[ti] = *(const ull2*)(bA + (wi * 4 + ti) * 1024 + lr * 256 + lc * 16);
    #pragma unroll
    for (int tj = 0; tj < 2; ++tj)
      bvv[tj] = *(const ull2*)(bB + (wj * 2 + tj) * 1024 + lr * 256 + lc * 16);
    #pragma unroll
    for (int m = 0; m < 2; ++m)
      #pragma unroll
      for (int ti = 0; ti < 4; ++ti)
        #pragma unroll
        for (int tj = 0; tj < 2; ++tj)
          acc[ti][tj] = __builtin_amdgcn_mfma_f32_16x16x32_fp8_fp8(
              (long)av[ti][m], (long)bvv[tj][m], acc[ti][tj], 0, 0, 0);
  }
  __syncthreads();              // all waves done with staging buffers
  if (mode == 3) {              // stage bsI into dead buf0
    #pragma unroll
    for (int e = 0; e < 4; ++e) {
      int flat = tid + e * 512;
      int row = flat & 127, w = flat >> 7;
      bsI[w * 128 + row] = bits[(size_t)(bi * 128 + row) * 16 + w];
    }
  }
  if (mode != 0) {              // stage bsJ into dead buf1
    #pragma unroll
    for (int e = 0; e < 4; ++e) {
      int flat = tid + e * 512;
      int row = flat & 127, w = flat >> 7;
      bsJ[w * 128 + row] = bits[(size_t)(bj * 128 + row) * 16 + w];
    }
  }
  __syncthreads();

  int tJv[2];
  #pragma unroll
  for (int tj = 0; tj < 2; ++tj) tJv[tj] = t1J[wj * 32 + tj * 16 + lc];

  float cs[2] = {0.f, 0.f};     // mirror column partial sums
  #pragma unroll
  for (int ti = 0; ti < 4; ++ti) {
    int ibase = wi * 64 + ti * 16 + lr * 4;
    unsigned inter[8];
    if (mode == 0) {            // conf x conf: intersect <=> same top1
      #pragma unroll
      for (int rr = 0; rr < 4; ++rr) {
        int tI = t1I[ibase + rr];
        #pragma unroll
        for (int tj = 0; tj < 2; ++tj) inter[rr * 2 + tj] = (tI == tJv[tj]);
      }
    } else if (mode == 1) {     // conf-I: probe J's bitset (scrambled mapping)
      #pragma unroll
      for (int rr = 0; rr < 4; ++rr) {
        int tI = t1I[ibase + rr];
        int w = ((tI >> 8) << 2) | (tI & 3);
        int bb = (tI >> 2) & 63;
        #pragma unroll
        for (int tj = 0; tj < 2; ++tj) {
          ull word = bsJ[w * 128 + wj * 32 + tj * 16 + lc];
          inter[rr * 2 + tj] = (unsigned)((word >> bb) & 1ULL);
        }
      }
    } else {                    // general: full 1024-bit AND (mapping-agnostic)
      #pragma unroll
      for (int q = 0; q < 8; ++q) inter[q] = 0u;
      #pragma unroll
      for (int w = 0; w < 16; ++w) {
        ull2 a01 = *(const ull2*)&bsI[w * 128 + ibase];
        ull2 a23 = *(const ull2*)&bsI[w * 128 + ibase + 2];
        ull aw[4] = {a01[0], a01[1], a23[0], a23[1]};
        ull bw[2];
        #pragma unroll
        for (int tj = 0; tj < 2; ++tj) bw[tj] = bsJ[w * 128 + wj * 32 + tj * 16 + lc];
        #pragma unroll
        for (int rr = 0; rr < 4; ++rr)
          #pragma unroll
          for (int tj = 0; tj < 2; ++tj) {
            ull t = aw[rr] & bw[tj];
            inter[rr * 2 + tj] |= (unsigned)(t | (t >> 32));
          }
      }
    }
    float rs[4] = {0.f, 0.f, 0.f, 0.f};
    #pragma unroll
    for (int rr = 0; rr < 4; ++rr)
      #pragma unroll
      for (int tj = 0; tj < 2; ++tj) {
        float sim = acc[ti][tj][rr];
        sim = fminf(sim, 1.0f);   // unit rows: math no-op
        float e_ = ((inter[rr * 2 + tj] == 0u) && (sim >= 1e-6f)) ? __expf(sim) : 0.f;
        rs[rr] += e_;
        cs[tj] += e_;
      }
    #pragma unroll
    for (int m = 1; m < 16; m <<= 1)
      #pragma unroll
      for (int rr = 0; rr < 4; ++rr) rs[rr] += __shfl_xor(rs[rr], m);
    if (lc == 0) {
      #pragma unroll
      for (int rr = 0; rr < 4; ++rr)
        atomicAdd(&S[(size_t)bi * 128 + ibase + rr], rs[rr]);
    }
  }
  if (bi != bj) {   // mirror: (j,i) identical by symmetry -> column sums
    #pragma unroll
    for (int tj = 0; tj < 2; ++tj) {
      cs[tj] += __shfl_xor(cs[tj], 16);   // reduce over lr
      cs[tj] += __shfl_xor(cs[tj], 32);
    }
    if (lr == 0) {
      #pragma unroll
      for (int tj = 0; tj < 2; ++tj)
        atomicAdd(&S[(size_t)bj * 128 + wj * 32 + tj * 16 + lc], cs[tj]);
    }
  }
}

// ---------------- KF: final reduction (loss + sc_num) — fp32 out -------------
__global__ __launch_bounds__(1024) void kf_final_v19(const float* __restrict__ possim,
                                                     const float* __restrict__ scsim,
                                                     const float* __restrict__ S,
                                                     const int* __restrict__ cnta,
                                                     const int* __restrict__ counters,
                                                     float* __restrict__ out) {
  __shared__ float red[1024];
  __shared__ int redi[1024];
  int tid = threadIdx.x;
  int nconf = counters[3];
  float local = 0.f;
  int lcnt = 0;
  for (int i = tid; i < N_ROWS; i += 1024) {
    float p = (i < nconf) ? possim[i] : scsim[i];
    p = fminf(fmaxf(p, -1.1f), 1.1f);      // |pos|<=1 math bound (safety)
    float s = fmaxf(S[i], 0.0f);
    local += logf(expf(p) + s) - p;        // -logp[:,0]
    lcnt += cnta[i];
  }
  red[tid] = local;
  redi[tid] = lcnt;
  __syncthreads();
  for (int s = 512; s > 0; s >>= 1) {
    if (tid < s) { red[tid] += red[tid + s]; redi[tid] += redi[tid + s]; }
    __syncthreads();
  }
  if (tid == 0) {
    float loss = red[0] / (float)N_ROWS;
    int denom = N_ROWS - nconf;            // exact: count of non-conf rows
    int scc = redi[0];
    float scn = (denom > 0) ? ((float)scc / (float)denom) : 0.f;
    out[0] = loss;
    out[1] = scn;
  }
}

extern "C" void kernel_launch(void* const* d_in, const int* in_sizes, int n_in,
                              void* d_out, int out_size, void* d_ws, size_t ws_size,
                              hipStream_t stream) {
  const float* feature   = (const float*)d_in[0];
  const float* proxy_raw = (const float*)d_in[1];
  const float* cP        = (const float*)d_in[2];
  const float* prob      = (const float*)d_in[3];
  const int*   conf      = (const int*)d_in[4];
  float* out = (float*)d_out;

  size_t need = (size_t)N_ROWS * DIM * 2      // featBF    8 MB (linear)
              + (size_t)N_ROWS * DIM          // featF8    4 MB (linear)
              + (size_t)C_PAD * DIM * 2       // proxyBF   1 MB (linear)
              + (size_t)N_ROWS * 16 * 8       // bits      1 MB
              + (size_t)N_ROWS * 4            // possim
              + (size_t)N_ROWS * 4            // S
              + (size_t)N_ROWS * 4            // scsim
              + 256                           // counters
              + (size_t)N_ROWS * 4            // perm
              + (size_t)N_ROWS * 4            // top1a
              + (size_t)N_ROWS * 4;           // cnta
  if (ws_size < need) return;

  char* ws = (char*)d_ws;
  __bf16* featBF  = (__bf16*)ws;              ws += (size_t)N_ROWS * DIM * 2;
  unsigned char* featF8 = (unsigned char*)ws; ws += (size_t)N_ROWS * DIM;
  __bf16* proxyBF = (__bf16*)ws;              ws += (size_t)C_PAD * DIM * 2;
  ull* bits       = (ull*)ws;                 ws += (size_t)N_ROWS * 16 * 8;
  float* possim   = (float*)ws;               ws += (size_t)N_ROWS * 4;
  float* S        = (float*)ws;               ws += (size_t)N_ROWS * 4;  // S,scsim,counters contiguous
  float* scsim    = (float*)ws;               ws += (size_t)N_ROWS * 4;
  int* counters   = (int*)ws;                 ws += 256;  // [3]=nconf
  int* perm       = (int*)ws;                 ws += (size_t)N_ROWS * 4;
  int* top1a      = (int*)ws;                 ws += (size_t)N_ROWS * 4;
  int* cnta       = (int*)ws;                 ws += (size_t)N_ROWS * 4;

  // kzp zeroes S+scsim+counters in-kernel (memset dispatch removed)
  kzp_v19<<<1, 1024, 0, stream>>>(conf, perm, counters, (int*)S);
  kda_v19<<<N_ROWS / 4, 256, 0, stream>>>(prob, feature, perm, counters,
                                          bits, top1a, cnta, featBF, featF8);
  kbc_v19<<<C_PAD / 8, 256, 0, stream>>>(proxy_raw, cP, proxyBF);
  kegg_v19<<<512 + 2080, 512, 0, stream>>>(featBF, proxyBF, featF8, prob, bits, perm,
                                           top1a, counters, scsim, possim, S);
  kf_final_v19<<<1, 1024, 0, stream>>>(possim, scsim, S, cnta, counters, out);
}